// Round 7
// baseline (473.044 us; speedup 1.0000x reference)
//
#include <hip/hip_runtime.h>
#include <hip/hip_fp16.h>
#include <math.h>

#define NN 100000
#define NE 3200000
#define NHEAD 4
#define HC 32
#define NG 512
#define EDGES (NE + NN)                 // 3,300,000

#define G1BLKS (NN / 8)                 // 12500

// ---- counting-sort CSR params ----
#define BKT_BITS 9
#define BKT_SIZE 512                    // nodes per bucket
#define NBKT 196                        // ceil(NN/512); 196*512 = 100352
#define CHUNK1 16384
#define NB1 ((EDGES + CHUNK1 - 1) / CHUNK1)   // 202
#define NB1S 204                        // padded row stride for CmatT
#define CAP2 18432                      // staging cap (mean 16896)
#define NBIN2 2048                      // 512 dstLow x 4 src-quarter
#define PCHUNK 128

__device__ __forceinline__ float lrelu(float x) { return x > 0.f ? x : 0.2f * x; }
__device__ __forceinline__ int src_quarter(int src) {
    return (src >= 50000) ? ((src >= 75000) ? 3 : 2) : ((src >= 25000) ? 1 : 0);
}

// ---------------- layer-1 GEMM (K=128), h stored fp16 ----------------
__global__ __launch_bounds__(256) void gemm1(
    const float* __restrict__ x, const float* __restrict__ W1,
    const float* __restrict__ as1, const float* __restrict__ ad1,
    __half* __restrict__ h, float* __restrict__ als, float* __restrict__ ald) {
    __shared__ float Wl[128 * HC];
    __shared__ float xl[8][128];
    int tid = threadIdx.x;
    for (int i = tid; i < 128 * HC; i += 256) Wl[i] = W1[i];
    int n0 = blockIdx.x * 8;
    {
        float4 v = *reinterpret_cast<const float4*>(x + n0 * 128 + tid * 4);
        int idx = tid * 4;
        int r = idx >> 7, c = idx & 127;
        *reinterpret_cast<float4*>(&xl[r][c]) = v;
    }
    __syncthreads();
    int r = tid >> 5, col = tid & 31;
    int n = n0 + r;
    float acc = 0.f;
#pragma unroll
    for (int k = 0; k < 128; ++k) acc = fmaf(xl[r][k], Wl[k * HC + col], acc);
    float s = acc * as1[col];
    float d = acc * ad1[col];
#pragma unroll
    for (int off = 1; off < 8; off <<= 1) {
        s += __shfl_xor(s, off);
        d += __shfl_xor(d, off);
    }
    h[n * HC + col] = __float2half(acc);
    if ((col & 7) == 0) {
        als[n * NHEAD + (col >> 3)] = s;
        ald[n * NHEAD + (col >> 3)] = d;
    }
}

// ---------------- CSR pass 1: bucket histogram (transposed count matrix) ----------
__global__ __launch_bounds__(512) void pass1_hist(const int* __restrict__ ei,
                                                  int* __restrict__ CmatT) {
    __shared__ int hcnt[NBKT];
    for (int i = threadIdx.x; i < NBKT; i += 512) hcnt[i] = 0;
    __syncthreads();
    int base = blockIdx.x * CHUNK1;
    int lim = min(base + CHUNK1, EDGES);
    for (int e = base + threadIdx.x; e < lim; e += 512) {
        int dst = (e < NE) ? ei[NE + e] : (e - NE);
        atomicAdd(&hcnt[dst >> BKT_BITS], 1);
    }
    __syncthreads();
    for (int i = threadIdx.x; i < NBKT; i += 512)
        CmatT[i * NB1S + blockIdx.x] = hcnt[i];
}

// one wave per bucket: exclusive scan of the 202 per-block counts
__global__ __launch_bounds__(64) void colscan2(int* __restrict__ CmatT,
                                               int* __restrict__ degTot) {
    int k = blockIdx.x;
    int lane = threadIdx.x;
    int* p = CmatT + k * NB1S;
    int i0 = lane * 4;
    int v0 = (i0 + 0 < NB1) ? p[i0 + 0] : 0;
    int v1 = (i0 + 1 < NB1) ? p[i0 + 1] : 0;
    int v2 = (i0 + 2 < NB1) ? p[i0 + 2] : 0;
    int v3 = (i0 + 3 < NB1) ? p[i0 + 3] : 0;
    int e1 = v0, e2 = v0 + v1, e3 = v0 + v1 + v2;
    int tot = e3 + v3;
    int run = tot;
#pragma unroll
    for (int off = 1; off < 64; off <<= 1) {
        int u = __shfl_up(run, off);
        if (lane >= off) run += u;
    }
    int excl = run - tot;
    if (i0 + 0 < NB1) p[i0 + 0] = excl;
    if (i0 + 1 < NB1) p[i0 + 1] = excl + e1;
    if (i0 + 2 < NB1) p[i0 + 2] = excl + e2;
    if (i0 + 3 < NB1) p[i0 + 3] = excl + e3;
    if (lane == 63) degTot[k] = run;
}

__global__ __launch_bounds__(256) void bucket_apex(const int* __restrict__ degTot,
                                                   int* __restrict__ bucketStart) {
    __shared__ int tot[256];
    int k = threadIdx.x;
    int own = (k < NBKT) ? degTot[k] : 0;
    tot[k] = own;
    __syncthreads();
    for (int off = 1; off < 256; off <<= 1) {
        int u = (k >= off) ? tot[k - off] : 0;
        __syncthreads();
        tot[k] += u;
        __syncthreads();
    }
    if (k < NBKT) bucketStart[k] = tot[k] - own;
    if (k == 255) bucketStart[NBKT] = tot[255];
}

// pass 1 scatter: dense per-(block,bucket) runs of packed (dstLow<<20 | src)
__global__ __launch_bounds__(512) void pass1_scatter(const int* __restrict__ ei,
                                                     const int* __restrict__ CmatT,
                                                     const int* __restrict__ bucketStart,
                                                     unsigned int* __restrict__ ebuf) {
    __shared__ int cur[NBKT];
    for (int i = threadIdx.x; i < NBKT; i += 512)
        cur[i] = bucketStart[i] + CmatT[i * NB1S + blockIdx.x];
    __syncthreads();
    int base = blockIdx.x * CHUNK1;
    int lim = min(base + CHUNK1, EDGES);
    for (int e = base + threadIdx.x; e < lim; e += 512) {
        int src, dst;
        if (e < NE) { src = ei[e]; dst = ei[NE + e]; }
        else        { src = dst = e - NE; }
        int pos = atomicAdd(&cur[dst >> BKT_BITS], 1);
        ebuf[pos] = ((unsigned int)(dst & (BKT_SIZE - 1)) << 20) | (unsigned int)src;
    }
}

// pass 2: per-bucket LDS sort by (dstLow, src-quarter) -> dense csrsrc + rowst.
// src-quarter ordering gives the agg kernel a phased (L2-resident) gather pattern.
__global__ __launch_bounds__(1024) void pass2_sort(const unsigned int* __restrict__ ebuf,
                                                   const int* __restrict__ bucketStart,
                                                   int* __restrict__ csrsrc,
                                                   int* __restrict__ rowst) {
    __shared__ int hist[NBIN2];
    __shared__ int pairs[1024];
    __shared__ int staging[CAP2];
    int t = threadIdx.x;
    int k = blockIdx.x;
    int start = bucketStart[k], end = bucketStart[k + 1];
    int count = end - start;
    hist[t] = 0;
    hist[t + 1024] = 0;
    __syncthreads();
    for (int i = start + t; i < end; i += 1024) {
        unsigned int v = ebuf[i];
        int src = (int)(v & 0xFFFFFu);
        atomicAdd(&hist[(int)((v >> 20) << 2) | src_quarter(src)], 1);
    }
    __syncthreads();
    int h0 = hist[2 * t], h1 = hist[2 * t + 1];
    pairs[t] = h0 + h1;
    __syncthreads();
    for (int off = 1; off < 1024; off <<= 1) {
        int u = (t >= off) ? pairs[t - off] : 0;
        __syncthreads();
        pairs[t] += u;
        __syncthreads();
    }
    int e0 = pairs[t] - h0 - h1;
    int e1 = e0 + h0;
    __syncthreads();
    hist[2 * t] = e0;
    hist[2 * t + 1] = e1;
    if ((t & 1) == 0) rowst[k * BKT_SIZE + (t >> 1)] = start + e0;
    __syncthreads();
    for (int i = start + t; i < end; i += 1024) {
        unsigned int v = ebuf[i];
        int src = (int)(v & 0xFFFFFu);
        int pos = atomicAdd(&hist[(int)((v >> 20) << 2) | src_quarter(src)], 1);
        if (pos < CAP2) staging[pos] = src;
    }
    __syncthreads();
    for (int i = t; i < count; i += 1024) csrsrc[start + i] = staging[i];
}

// ---------------- lane-split single-pass GAT aggregation ----------------
// 16-edge chunks: lane (head*8+slot) computes p for edges slot, slot+8 (2 expf
// per lane per 16 edges); 16 batched h-gathers in flight per group.
template<bool FUSE>
__global__ __launch_bounds__(256) void agg_layer(
    const int* __restrict__ rowst, const int* __restrict__ csrsrc,
    const float* __restrict__ als, const float* __restrict__ ald,
    const __half* __restrict__ h, const float* __restrict__ bias,
    const float* __restrict__ Wn, const float* __restrict__ asn,
    const float* __restrict__ adn,
    __half* __restrict__ h_out, float* __restrict__ als_out,
    float* __restrict__ ald_out, float* __restrict__ act_out) {
    __shared__ float Wl[HC * HC];
    int tid = threadIdx.x;
    if (FUSE) {
        for (int i = tid; i < HC * HC; i += 256) Wl[i] = Wn[i];
        __syncthreads();
    }
    int g = blockIdx.x * 8 + (tid >> 5);
    int lane = tid & 31;
    int head = lane >> 3;
    int slot = lane & 7;
    float adh = ald[g * NHEAD + head];
    int beg = rowst[g], end = rowst[g + 1];

    float acc[8];
#pragma unroll
    for (int j = 0; j < 8; ++j) acc[j] = 0.f;
    float dsum = 0.f;
    const __half* hL = h + lane;

    for (int c0 = beg; c0 < end; c0 += 16) {
        int eA = c0 + slot;
        int eB = eA + 8;
        int sA = (eA < end) ? __builtin_nontemporal_load(csrsrc + eA) : 0;
        int sB = (eB < end) ? __builtin_nontemporal_load(csrsrc + eB) : 0;
        float pA = __expf(lrelu(als[sA * NHEAD + head] + adh));
        float pB = __expf(lrelu(als[sB * NHEAD + head] + adh));
        pA = (eA < end) ? pA : 0.f;
        pB = (eB < end) ? pB : 0.f;
        dsum += pA + pB;
        int sjA[8], sjB[8];
#pragma unroll
        for (int j = 0; j < 8; ++j) {
            sjA[j] = __shfl(sA, j, 32);
            sjB[j] = __shfl(sB, j, 32);
        }
        __half hvA[8], hvB[8];
#pragma unroll
        for (int j = 0; j < 8; ++j) hvA[j] = hL[sjA[j] * HC];
#pragma unroll
        for (int j = 0; j < 8; ++j) hvB[j] = hL[sjB[j] * HC];
#pragma unroll
        for (int j = 0; j < 8; ++j)
            acc[j] = fmaf(__shfl(pA, (head << 3) | j, 32), __half2float(hvA[j]), acc[j]);
#pragma unroll
        for (int j = 0; j < 8; ++j)
            acc[j] = fmaf(__shfl(pB, (head << 3) | j, 32), __half2float(hvB[j]), acc[j]);
    }
    float a = ((acc[0] + acc[1]) + (acc[2] + acc[3])) +
              ((acc[4] + acc[5]) + (acc[6] + acc[7]));
    dsum += __shfl_xor(dsum, 1, 32);
    dsum += __shfl_xor(dsum, 2, 32);
    dsum += __shfl_xor(dsum, 4, 32);

    float v = a / dsum + bias[lane];
    float av = v > 0.f ? v : (__expf(v) - 1.f);
    if (!FUSE) {
        act_out[g * HC + lane] = av;
        return;
    }
    float hacc = 0.f;
#pragma unroll
    for (int kk = 0; kk < HC; ++kk)
        hacc = fmaf(__shfl(av, kk, 32), Wl[kk * HC + lane], hacc);
    h_out[g * HC + lane] = __float2half(hacc);
    float sv = hacc * asn[lane];
    float dv = hacc * adn[lane];
#pragma unroll
    for (int off = 1; off < 8; off <<= 1) {
        sv += __shfl_xor(sv, off);
        dv += __shfl_xor(dv, off);
    }
    if ((lane & 7) == 0) {
        als_out[g * NHEAD + head] = sv;
        ald_out[g * NHEAD + head] = dv;
    }
}

// ---------------- pooling (sorted batch) + FC ----------------
__global__ void pool_init(float* __restrict__ sums, float* __restrict__ cnt) {
    int i = blockIdx.x * blockDim.x + threadIdx.x;
    if (i < NG * HC) sums[i] = 0.f;
    if (i < NG) cnt[i] = 0.f;
}

__global__ __launch_bounds__(256) void pool_seg(const float* __restrict__ act,
                                                const int* __restrict__ batch,
                                                float* __restrict__ sums,
                                                float* __restrict__ cnt) {
    int grp = blockIdx.x * 8 + (threadIdx.x >> 5);
    int lane = threadIdx.x & 31;
    int n0 = grp * PCHUNK;
    if (n0 >= NN) return;
    int n1 = min(n0 + PCHUNK, NN);
    int curg = batch[n0];
    float acc = 0.f, c = 0.f;
    for (int n = n0; n < n1; ++n) {
        int gg = batch[n];
        if (gg != curg) {
            atomicAdd(&sums[curg * HC + lane], acc);
            if (lane == 0) atomicAdd(&cnt[curg], c);
            acc = 0.f; c = 0.f; curg = gg;
        }
        acc += act[n * HC + lane];
        c += 1.f;
    }
    atomicAdd(&sums[curg * HC + lane], acc);
    if (lane == 0) atomicAdd(&cnt[curg], c);
}

__global__ void fc_out(const float* __restrict__ sums, const float* __restrict__ cnt,
                       const float* __restrict__ fcw, const float* __restrict__ fcb,
                       float* __restrict__ out) {
    int g = blockIdx.x;
    int lane = threadIdx.x;
    float v = (lane < HC) ? sums[g * HC + lane] * fcw[lane] : 0.f;
#pragma unroll
    for (int off = 32; off; off >>= 1) v += __shfl_down(v, off);
    if (lane == 0) out[g] = v / fmaxf(cnt[g], 1.f) + fcb[0];
}

extern "C" void kernel_launch(void* const* d_in, const int* in_sizes, int n_in,
                              void* d_out, int out_size, void* d_ws, size_t ws_size,
                              hipStream_t stream) {
    const float* x     = (const float*)d_in[0];
    const int*   ei    = (const int*)d_in[1];
    const int*   batch = (const int*)d_in[2];
    const float* W[4]   = {(const float*)d_in[3],  (const float*)d_in[7],
                           (const float*)d_in[11], (const float*)d_in[15]};
    const float* asr[4] = {(const float*)d_in[4],  (const float*)d_in[8],
                           (const float*)d_in[12], (const float*)d_in[16]};
    const float* adt[4] = {(const float*)d_in[5],  (const float*)d_in[9],
                           (const float*)d_in[13], (const float*)d_in[17]};
    const float* bb[4]  = {(const float*)d_in[6],  (const float*)d_in[10],
                           (const float*)d_in[14], (const float*)d_in[18]};
    const float* fcw = (const float*)d_in[19];
    const float* fcb = (const float*)d_in[20];
    float* out = (float*)d_out;

    char* ws = (char*)d_ws;
    size_t off = 0;
    auto carve = [&](size_t bytes) {
        void* p = ws + off;
        off += (bytes + 255) & ~size_t(255);
        return p;
    };
    __half* hA   = (__half*)carve(sizeof(__half) * NN * HC);
    __half* hB   = (__half*)carve(sizeof(__half) * NN * HC);
    float* actF  = (float*)carve(sizeof(float) * NN * HC);
    float* alsA  = (float*)carve(sizeof(float) * NN * NHEAD);
    float* aldA  = (float*)carve(sizeof(float) * NN * NHEAD);
    float* alsB  = (float*)carve(sizeof(float) * NN * NHEAD);
    float* aldB  = (float*)carve(sizeof(float) * NN * NHEAD);
    int*   CmatT = (int*)carve(sizeof(int) * NBKT * NB1S);
    int*   degTot= (int*)carve(sizeof(int) * NBKT);
    int*   bkst  = (int*)carve(sizeof(int) * (NBKT + 1));
    unsigned int* ebuf = (unsigned int*)carve(sizeof(unsigned int) * EDGES);
    int*   rowst = (int*)carve(sizeof(int) * NBKT * BKT_SIZE);
    int*   csrsrc= (int*)carve(sizeof(int) * EDGES);
    float* sums  = (float*)carve(sizeof(float) * NG * HC);
    float* cnt   = (float*)carve(sizeof(float) * NG);

    // ---- CSR build: 2-pass counting sort, dense writes ----
    pass1_hist<<<NB1, 512, 0, stream>>>(ei, CmatT);
    colscan2<<<NBKT, 64, 0, stream>>>(CmatT, degTot);
    bucket_apex<<<1, 256, 0, stream>>>(degTot, bkst);
    pass1_scatter<<<NB1, 512, 0, stream>>>(ei, CmatT, bkst, ebuf);
    pass2_sort<<<NBKT, 1024, 0, stream>>>(ebuf, bkst, csrsrc, rowst);

    // ---- layer-1 GEMM ----
    gemm1<<<G1BLKS, 256, 0, stream>>>(x, W[0], asr[0], adt[0], hA, alsA, aldA);

    // ---- 4 GAT layers: agg(L) fused with gemm(L+1) ----
    agg_layer<true><<<G1BLKS, 256, 0, stream>>>(rowst, csrsrc, alsA, aldA, hA, bb[0],
                                                W[1], asr[1], adt[1],
                                                hB, alsB, aldB, nullptr);
    agg_layer<true><<<G1BLKS, 256, 0, stream>>>(rowst, csrsrc, alsB, aldB, hB, bb[1],
                                                W[2], asr[2], adt[2],
                                                hA, alsA, aldA, nullptr);
    agg_layer<true><<<G1BLKS, 256, 0, stream>>>(rowst, csrsrc, alsA, aldA, hA, bb[2],
                                                W[3], asr[3], adt[3],
                                                hB, alsB, aldB, nullptr);
    agg_layer<false><<<G1BLKS, 256, 0, stream>>>(rowst, csrsrc, alsB, aldB, hB, bb[3],
                                                 nullptr, nullptr, nullptr,
                                                 nullptr, nullptr, nullptr, actF);

    // ---- global mean pool + FC ----
    pool_init<<<(NG * HC + 255) / 256, 256, 0, stream>>>(sums, cnt);
    pool_seg<<<((NN + PCHUNK - 1) / PCHUNK + 7) / 8, 256, 0, stream>>>(actF, batch,
                                                                       sums, cnt);
    fc_out<<<NG, 64, 0, stream>>>(sums, cnt, fcw, fcb, out);
}